// Round 6
// baseline (250.872 us; speedup 1.0000x reference)
//
#include <hip/hip_runtime.h>

#define BN 4
#define LN 1024
#define SN 1024
#define HN 8
#define EN 64
#define OFF_ATT (BN * LN * HN * EN)
#define OFF_ENT (OFF_ATT + BN * HN * LN * SN)

// workspace byte offsets (need 8.4 MB)
#define WS_KB 0u
#define WS_VT 4194304u

typedef __attribute__((ext_vector_type(8))) __bf16 bf16x8;
typedef __attribute__((ext_vector_type(4))) float f32x4;
typedef __attribute__((ext_vector_type(4))) unsigned int uint4v;
typedef __attribute__((ext_vector_type(2))) unsigned int uint2v;

// blockIdx.x encodes (lbHi, b, lbLo): batch-siblings of an (h,l-tile) are 8
// blocks apart -> same XCD under round-robin -> shared phi/u slices L2-hot.
__device__ __forceinline__ void decode_block(int x, int& b, int& lb) {
  int lbLo = x & 7;
  b = (x >> 3) & 3;
  lb = (x >> 5) * 8 + lbLo;
}

// 8 consecutive floats -> packed bf16 hi + lo (trunc split)
__device__ __forceinline__ void cvt8(const float* p, uint4v& hv, uint4v& lv) {
  float4 a = *(const float4*)p;
  float4 bq = *(const float4*)(p + 4);
  float x[8] = {a.x, a.y, a.z, a.w, bq.x, bq.y, bq.z, bq.w};
  unsigned int h[8], lo[8];
#pragma unroll
  for (int i = 0; i < 8; ++i) {
    unsigned int ub = __float_as_uint(x[i]);
    h[i] = ub >> 16;
    float lf = x[i] - __uint_as_float(ub & 0xffff0000u);
    lo[i] = __float_as_uint(lf) >> 16;
  }
  hv = uint4v{h[0] | (h[1] << 16), h[2] | (h[3] << 16),
              h[4] | (h[5] << 16), h[6] | (h[7] << 16)};
  lv = uint4v{lo[0] | (lo[1] << 16), lo[2] | (lo[3] << 16),
              lo[4] | (lo[5] << 16), lo[6] | (lo[7] << 16)};
}

__device__ __forceinline__ uint4v pack8_trunc(float4 a, float4 b) {
  return uint4v{(__float_as_uint(a.x) >> 16) | (__float_as_uint(a.y) & 0xffff0000u),
                (__float_as_uint(a.z) >> 16) | (__float_as_uint(a.w) & 0xffff0000u),
                (__float_as_uint(b.x) >> 16) | (__float_as_uint(b.y) & 0xffff0000u),
                (__float_as_uint(b.z) >> 16) | (__float_as_uint(b.w) & 0xffff0000u)};
}

// ---------------- prep kernels ----------------

// K [b,s,h,e] fp32 -> kb [b][h][s][e] bf16 (single, truncation)
__global__ __launch_bounds__(256) void k_kprep(const float* __restrict__ kk,
                                               unsigned short* __restrict__ kb) {
  int gid = blockIdx.x * 256 + threadIdx.x;  // 262144 groups of 8 elements
  int e8 = gid & 7;
  int tmp = gid >> 3;
  int h = tmp & 7;
  int bs = tmp >> 3;
  int s = bs & 1023;
  int b = bs >> 10;
  const float* src = kk + (size_t)gid * 8;
  float4 a = *(const float4*)src;
  float4 bq = *(const float4*)(src + 4);
  *(uint4v*)(kb + (((size_t)(b * 8 + h) * 1024 + s) * 64) + e8 * 8) =
      pack8_trunc(a, bq);
}

// V [b,s,h,e] fp32 -> vT [b][h][e][s] bf16 (transpose)
__global__ __launch_bounds__(256) void k_vprep(const float* __restrict__ vv,
                                               unsigned short* __restrict__ vT) {
  int gid = blockIdx.x * 256 + threadIdx.x;  // 262144 groups of 8 s
  int s8 = gid & 127;
  int t1 = gid >> 7;
  int e = t1 & 63;
  int t2 = t1 >> 6;
  int h = t2 & 7;
  int b = t2 >> 3;
  float x[8];
#pragma unroll
  for (int j = 0; j < 8; ++j)
    x[j] = vv[((size_t)(b * 1024 + s8 * 8 + j) * 8 + h) * 64 + e];
  uint4v pv = pack8_trunc(float4{x[0], x[1], x[2], x[3]},
                          float4{x[4], x[5], x[6], x[7]});
  *(uint4v*)(vT + ((size_t)(b * 8 + h) * 64 + e) * 1024 + s8 * 8) = pv;
}

// ---------------- fused scores + mask + softmax + entropy + PV ----------------
// Block = 4 waves, 16 q-rows of one (b,h). Swapped QK^T (D = K*Q): lane
// (cl,cg) owns q-row l=lb*16+cl, s = w*256 + tg*16 + cg*4..+3 (wave w owns
// s-range [w*256, w*256+256)). Gumbel-sigmoid mask computed inline (VALU is
// idle; saves a kernel + mw array). After softmax, full 16x1024 att tile in
// LDS (bf16, XOR-swizzled); one barrier; e-split PV: wave w computes the
// complete s-sum for e in [w*16, w*16+16) -> one 16x16 MFMA acc pair, direct
// output store, no cross-wave reduce.
__global__ __launch_bounds__(256, 4) void k_fused(
    const float* __restrict__ q, const unsigned short* __restrict__ kb,
    const unsigned short* __restrict__ vT, const float* __restrict__ phi,
    const float* __restrict__ uarr, const float* __restrict__ p_logtau,
    const float* __restrict__ p_thresh, const float* __restrict__ pos,
    const int* __restrict__ p_causal, float* __restrict__ out) {
  int b, lb;
  decode_block(blockIdx.x, b, lb);
  const int h = blockIdx.y;
  const int tid = threadIdx.x;
  const int w = __builtin_amdgcn_readfirstlane(tid >> 6);
  const int c = tid & 63;
  const int cl = c & 15;
  const int cg = c >> 4;

  // full att tile [16 rows][1024 s] bf16, row stride 2048 B, XOR-swizzled
  __shared__ __align__(16) unsigned char lds_att[32768];
  __shared__ float red0[4][16], redZ[4][16], redE[4][16];

  const float tau = fminf(fmaxf(__expf(p_logtau[0]), 0.1f), 5.0f);
  const float rtau = 1.0f / tau;
  const float thr = fminf(fmaxf(p_thresh[0], 0.01f), 0.99f);
  const int causal = p_causal[0];
  const int l = lb * 16 + cl;  // this lane's q-row

  // Q fragments (B operand): n = cl (q-row), k = cg*8+j within 32-chunk
  uint4v qh[2], ql[2];
#pragma unroll
  for (int cc = 0; cc < 2; ++cc) {
    const float* qp = q + (((size_t)b * LN + l) * HN + h) * EN + cc * 32 + cg * 8;
    cvt8(qp, qh[cc], ql[cc]);
  }

  const unsigned short* kbb = kb + ((size_t)(b * 8 + h) * 1024) * 64;
  f32x4 accs[16];

  // ---- QK^T: batches of 4 tiles -> 8 loads in flight, then 16 MFMAs
#pragma unroll
  for (int tgb = 0; tgb < 4; ++tgb) {
    uint4v kf[4][2];
#pragma unroll
    for (int t2 = 0; t2 < 4; ++t2) {
      const int row = w * 256 + (tgb * 4 + t2) * 16 + cl;
#pragma unroll
      for (int cc = 0; cc < 2; ++cc)
        kf[t2][cc] = *(const uint4v*)(kbb + (size_t)row * 64 + cc * 32 + cg * 8);
    }
#pragma unroll
    for (int t2 = 0; t2 < 4; ++t2) {
      f32x4 acc = f32x4{0.f, 0.f, 0.f, 0.f};
#pragma unroll
      for (int cc = 0; cc < 2; ++cc) {
        bf16x8 kv = __builtin_bit_cast(bf16x8, kf[t2][cc]);
        acc = __builtin_amdgcn_mfma_f32_16x16x32_bf16(
            kv, __builtin_bit_cast(bf16x8, qh[cc]), acc, 0, 0, 0);
        acc = __builtin_amdgcn_mfma_f32_16x16x32_bf16(
            kv, __builtin_bit_cast(bf16x8, ql[cc]), acc, 0, 0, 0);
      }
      accs[tgb * 4 + t2] = acc;
    }
  }

  // ---- inline gumbel-sigmoid mask + causal + max
  const float* posb = pos + b * LN;
  const float plr = posb[l];
  const float* ub = uarr + ((size_t)h * LN + l) * SN;
  const float* pb = phi + ((size_t)h * LN + l) * SN;

  float mx = -3.0e38f;
#pragma unroll
  for (int tg = 0; tg < 16; ++tg) {
    const int s0 = w * 256 + tg * 16 + cg * 4;
    float4 u4 = *(const float4*)(ub + s0);
    float4 p4 = *(const float4*)(pb + s0);
    float4 po4 = *(const float4*)(posb + s0);
    float uu[4] = {u4.x, u4.y, u4.z, u4.w};
    float pp[4] = {p4.x, p4.y, p4.z, p4.w};
    float pov[4] = {po4.x, po4.y, po4.z, po4.w};
#pragma unroll
    for (int r = 0; r < 4; ++r) {
      float g = __logf(__fdividef(uu[r] + 1e-8f, 1.0f - uu[r] + 1e-8f));
      float z = (g + pp[r]) * rtau;
      float sig = __fdividef(1.0f, 1.0f + __expf(-z));
      float pm = -10000.0f * fmaxf(thr - sig, 0.0f) * 0.125f;
      float v = fmaf(accs[tg][r], 0.125f, pm);
      bool maskd = (causal != 0) && (pov[r] > plr);
      v = maskd ? -1.0e30f : v;
      accs[tg][r] = v;
      mx = fmaxf(mx, v);
    }
  }
  mx = fmaxf(mx, __shfl_xor(mx, 16, 64));
  mx = fmaxf(mx, __shfl_xor(mx, 32, 64));
  if (cg == 0) red0[w][cl] = mx;
  __syncthreads();
  const float bmx = fmaxf(fmaxf(red0[0][cl], red0[1][cl]),
                          fmaxf(red0[2][cl], red0[3][cl]));

  float zz = 0.f, ee = 0.f;
#pragma unroll
  for (int tg = 0; tg < 16; ++tg) {
#pragma unroll
    for (int r = 0; r < 4; ++r) {
      float tt = accs[tg][r] - bmx;
      float ex = __expf(tt);
      zz += ex;
      ee = fmaf(ex, fmaxf(tt, -88.0f), ee);  // guard 0 * -1e30
      accs[tg][r] = ex;
    }
  }
  zz += __shfl_xor(zz, 16, 64);
  zz += __shfl_xor(zz, 32, 64);
  ee += __shfl_xor(ee, 16, 64);
  ee += __shfl_xor(ee, 32, 64);
  if (cg == 0) { redZ[w][cl] = zz; redE[w][cl] = ee; }
  __syncthreads();
  const float Z = redZ[0][cl] + redZ[1][cl] + redZ[2][cl] + redZ[3][cl];
  const float E = redE[0][cl] + redE[1][cl] + redE[2][cl] + redE[3][cl];
  const float rz = __fdividef(1.0f, Z);

  // ---- att store (global fp32) + normalized bf16 into swizzled LDS
  float* ab = out + OFF_ATT + (((size_t)b * HN + h) * LN + l) * SN;
  const int swz = (cl & 7) << 4;
  unsigned char* arow = lds_att + cl * 2048;
#pragma unroll
  for (int tg = 0; tg < 16; ++tg) {
    const int s0 = w * 256 + tg * 16 + cg * 4;
    float4 av = float4{accs[tg][0] * rz, accs[tg][1] * rz,
                       accs[tg][2] * rz, accs[tg][3] * rz};
    *(float4*)(ab + s0) = av;
    uint2v pk = uint2v{
        (__float_as_uint(av.x) >> 16) | (__float_as_uint(av.y) & 0xffff0000u),
        (__float_as_uint(av.z) >> 16) | (__float_as_uint(av.w) & 0xffff0000u)};
    *(uint2v*)(arow + ((s0 * 2) ^ swz)) = pk;
  }
  if (w == 0 && cg == 0)
    out[OFF_ENT + ((size_t)b * HN + h) * LN + l] = __logf(Z) - E * rz;

  __syncthreads();  // full att tile visible

  // ---- e-split PV: wave w owns e in [w*16, w*16+16). One 16x16 D tile:
  // A = vT frag (m = e-local = cl, k = cg*8+j), B = att LDS frag (n = cl,
  // k = cg*8+j). 32 chunks of 32 s, alternating acc chains.
  const unsigned short* vbb =
      vT + ((size_t)(b * 8 + h) * 64 + w * 16 + cl) * 1024;
  f32x4 acc0 = f32x4{0.f, 0.f, 0.f, 0.f};
  f32x4 acc1 = f32x4{0.f, 0.f, 0.f, 0.f};
#pragma unroll
  for (int scb = 0; scb < 8; ++scb) {
    uint4v vf[4], af[4];
#pragma unroll
    for (int j = 0; j < 4; ++j) {
      const int sc = scb * 4 + j;
      vf[j] = *(const uint4v*)(vbb + sc * 32 + cg * 8);
      af[j] = *(const uint4v*)(arow + (((sc * 32 + cg * 8) * 2) ^ swz));
    }
#pragma unroll
    for (int j = 0; j < 4; ++j) {
      bf16x8 a8 = __builtin_bit_cast(bf16x8, vf[j]);
      bf16x8 b8 = __builtin_bit_cast(bf16x8, af[j]);
      if (j & 1)
        acc1 = __builtin_amdgcn_mfma_f32_16x16x32_bf16(a8, b8, acc1, 0, 0, 0);
      else
        acc0 = __builtin_amdgcn_mfma_f32_16x16x32_bf16(a8, b8, acc0, 0, 0, 0);
    }
  }
  f32x4 sum = acc0 + acc1;
  // D: col = cl = q-row, row = cg*4+r = e-local -> 4 contiguous e per lane
  *(f32x4*)(out + (((size_t)b * LN + l) * HN + h) * EN + w * 16 + cg * 4) = sum;
}

extern "C" void kernel_launch(void* const* d_in, const int* in_sizes, int n_in,
                              void* d_out, int out_size, void* d_ws, size_t ws_size,
                              hipStream_t stream) {
  (void)in_sizes; (void)n_in; (void)out_size; (void)ws_size;
  const float* q   = (const float*)d_in[0];
  const float* k   = (const float*)d_in[1];
  const float* v   = (const float*)d_in[2];
  const float* pos = (const float*)d_in[3];
  const float* phi = (const float*)d_in[4];
  const float* u   = (const float*)d_in[5];
  const float* lt  = (const float*)d_in[6];
  const float* th  = (const float*)d_in[7];
  const int*   cm  = (const int*)d_in[8];
  float* out = (float*)d_out;

  unsigned short* kb = (unsigned short*)((char*)d_ws + WS_KB);
  unsigned short* vT = (unsigned short*)((char*)d_ws + WS_VT);

  dim3 blk(256, 1, 1);
  k_kprep<<<dim3(1024), blk, 0, stream>>>(k, kb);
  k_vprep<<<dim3(1024), blk, 0, stream>>>(v, vT);
  k_fused<<<dim3(256, 8, 1), blk, 0, stream>>>(q, kb, vT, phi, u, lt, th, pos,
                                               cm, out);
}

// Round 7
// 157.695 us; speedup vs baseline: 1.5909x; 1.5909x over previous
//
#include <hip/hip_runtime.h>

#define BN 4
#define LN 1024
#define SN 1024
#define HN 8
#define EN 64
#define OFF_ATT (BN * LN * HN * EN)
#define OFF_ENT (OFF_ATT + BN * HN * LN * SN)

// workspace byte offsets (need ~25 MB)
#define WS_MW 0u                          // f16 mask, 8*1024*1024*2 = 16 MB
#define WS_KB 16777216u                   // bf16 K, 4 MB
#define WS_VT (WS_KB + 4194304u)          // bf16 V^T, 4 MB

// att LDS tile: 16 rows, pitch 2064 B (516 dwords == 4 mod 32 banks ->
// 16 rows hit 8 distinct 4-bank groups, 2 rows each: 2-way = free)
#define APITCH 2064

typedef __attribute__((ext_vector_type(8))) __bf16 bf16x8;
typedef __attribute__((ext_vector_type(4))) float f32x4;
typedef __attribute__((ext_vector_type(4))) unsigned int uint4v;
typedef __attribute__((ext_vector_type(2))) unsigned int uint2v;
typedef __attribute__((ext_vector_type(4))) _Float16 f16x4;

// blockIdx.x encodes (lbHi, b, lbLo): batch-siblings of an (h,l-tile) are 8
// blocks apart -> same XCD under round-robin -> shared mw slices L2-hot.
__device__ __forceinline__ void decode_block(int x, int& b, int& lb) {
  int lbLo = x & 7;
  b = (x >> 3) & 3;
  lb = (x >> 5) * 8 + lbLo;
}

// 8 consecutive floats -> packed bf16 hi + lo (trunc split)
__device__ __forceinline__ void cvt8(const float* p, uint4v& hv, uint4v& lv) {
  float4 a = *(const float4*)p;
  float4 bq = *(const float4*)(p + 4);
  float x[8] = {a.x, a.y, a.z, a.w, bq.x, bq.y, bq.z, bq.w};
  unsigned int h[8], lo[8];
#pragma unroll
  for (int i = 0; i < 8; ++i) {
    unsigned int ub = __float_as_uint(x[i]);
    h[i] = ub >> 16;
    float lf = x[i] - __uint_as_float(ub & 0xffff0000u);
    lo[i] = __float_as_uint(lf) >> 16;
  }
  hv = uint4v{h[0] | (h[1] << 16), h[2] | (h[3] << 16),
              h[4] | (h[5] << 16), h[6] | (h[7] << 16)};
  lv = uint4v{lo[0] | (lo[1] << 16), lo[2] | (lo[3] << 16),
              lo[4] | (lo[5] << 16), lo[6] | (lo[7] << 16)};
}

__device__ __forceinline__ uint4v pack8_trunc(float4 a, float4 b) {
  return uint4v{(__float_as_uint(a.x) >> 16) | (__float_as_uint(a.y) & 0xffff0000u),
                (__float_as_uint(a.z) >> 16) | (__float_as_uint(a.w) & 0xffff0000u),
                (__float_as_uint(b.x) >> 16) | (__float_as_uint(b.y) & 0xffff0000u),
                (__float_as_uint(b.z) >> 16) | (__float_as_uint(b.w) & 0xffff0000u)};
}

// ---------------- prep kernels ----------------

// phi-mask (f16): pm = -10000*relu(thr - sigmoid((gumbel+phi)/tau)) * 0.125
__global__ __launch_bounds__(256) void k_mask_prep(
    const float* __restrict__ phi, const float* __restrict__ u,
    const float* __restrict__ p_logtau, const float* __restrict__ p_thresh,
    _Float16* __restrict__ mw) {
  const float tau = fminf(fmaxf(__expf(p_logtau[0]), 0.1f), 5.0f);
  const float rtau = 1.0f / tau;
  const float thr = fminf(fmaxf(p_thresh[0], 0.01f), 0.99f);
  int idx = (blockIdx.x * 256 + threadIdx.x) * 4;
  float4 u4 = *(const float4*)(u + idx);
  float4 p4 = *(const float4*)(phi + idx);
  float uu[4] = {u4.x, u4.y, u4.z, u4.w};
  float pp[4] = {p4.x, p4.y, p4.z, p4.w};
  f16x4 o;
#pragma unroll
  for (int i = 0; i < 4; ++i) {
    float g = __logf(__fdividef(uu[i] + 1e-8f, 1.0f - uu[i] + 1e-8f));
    float z = (g + pp[i]) * rtau;
    float sig = __fdividef(1.0f, 1.0f + __expf(-z));
    o[i] = (_Float16)(-10000.0f * fmaxf(thr - sig, 0.0f) * 0.125f);
  }
  *(f16x4*)(mw + idx) = o;
}

// K [b,s,h,e] fp32 -> kb [b][h][s][e] bf16 (single, truncation)
__global__ __launch_bounds__(256) void k_kprep(const float* __restrict__ kk,
                                               unsigned short* __restrict__ kb) {
  int gid = blockIdx.x * 256 + threadIdx.x;
  int e8 = gid & 7;
  int tmp = gid >> 3;
  int h = tmp & 7;
  int bs = tmp >> 3;
  int s = bs & 1023;
  int b = bs >> 10;
  const float* src = kk + (size_t)gid * 8;
  float4 a = *(const float4*)src;
  float4 bq = *(const float4*)(src + 4);
  *(uint4v*)(kb + (((size_t)(b * 8 + h) * 1024 + s) * 64) + e8 * 8) =
      pack8_trunc(a, bq);
}

// V [b,s,h,e] fp32 -> vT [b][h][e][s] bf16 (transpose)
__global__ __launch_bounds__(256) void k_vprep(const float* __restrict__ vv,
                                               unsigned short* __restrict__ vT) {
  int gid = blockIdx.x * 256 + threadIdx.x;
  int s8 = gid & 127;
  int t1 = gid >> 7;
  int e = t1 & 63;
  int t2 = t1 >> 6;
  int h = t2 & 7;
  int b = t2 >> 3;
  float x[8];
#pragma unroll
  for (int j = 0; j < 8; ++j)
    x[j] = vv[((size_t)(b * 1024 + s8 * 8 + j) * 8 + h) * 64 + e];
  uint4v pv = pack8_trunc(float4{x[0], x[1], x[2], x[3]},
                          float4{x[4], x[5], x[6], x[7]});
  *(uint4v*)(vT + ((size_t)(b * 8 + h) * 64 + e) * 1024 + s8 * 8) = pv;
}

// ---------------- fused scores + mask + softmax + entropy + PV ----------------
// Block = 4 waves, 16 q-rows of one (b,h). Swapped QK^T (D = K*Q): lane
// (cl,cg) owns q-row l=lb*16+cl, s = w*256 + tg*16 + cg*4..+3. After softmax,
// full 16x1024 normalized att tile in LDS (bf16, pitch 2064); one barrier;
// then (a) coalesced fp32 att write (wave w -> rows w*4..w*4+3, float4
// streams) and (b) e-split PV: wave w owns e in [w*16,w*16+16), full s-sum
// via one 16x16 MFMA acc pair, direct store, no cross-wave reduce.
__global__ __launch_bounds__(256, 4) void k_fused(
    const float* __restrict__ q, const unsigned short* __restrict__ kb,
    const unsigned short* __restrict__ vT, const _Float16* __restrict__ mw,
    const float* __restrict__ pos, const int* __restrict__ p_causal,
    float* __restrict__ out) {
  int b, lb;
  decode_block(blockIdx.x, b, lb);
  const int h = blockIdx.y;
  const int tid = threadIdx.x;
  const int w = __builtin_amdgcn_readfirstlane(tid >> 6);
  const int c = tid & 63;
  const int cl = c & 15;
  const int cg = c >> 4;

  __shared__ __align__(16) unsigned char lds_att[16 * APITCH];
  __shared__ float red0[4][16], redZ[4][16], redE[4][16];

  const int causal = p_causal[0];
  const int l = lb * 16 + cl;  // this lane's q-row

  // Q fragments (B operand): n = cl (q-row), k = cg*8+j within 32-chunk
  uint4v qh[2], ql[2];
#pragma unroll
  for (int cc = 0; cc < 2; ++cc) {
    const float* qp = q + (((size_t)b * LN + l) * HN + h) * EN + cc * 32 + cg * 8;
    cvt8(qp, qh[cc], ql[cc]);
  }

  const unsigned short* kbb = kb + ((size_t)(b * 8 + h) * 1024) * 64;
  f32x4 accs[16];

  // ---- QK^T: batches of 4 tiles -> 8 loads in flight, then 16 MFMAs
#pragma unroll
  for (int tgb = 0; tgb < 4; ++tgb) {
    uint4v kf[4][2];
#pragma unroll
    for (int t2 = 0; t2 < 4; ++t2) {
      const int row = w * 256 + (tgb * 4 + t2) * 16 + cl;
#pragma unroll
      for (int cc = 0; cc < 2; ++cc)
        kf[t2][cc] = *(const uint4v*)(kbb + (size_t)row * 64 + cc * 32 + cg * 8);
    }
#pragma unroll
    for (int t2 = 0; t2 < 4; ++t2) {
      f32x4 acc = f32x4{0.f, 0.f, 0.f, 0.f};
#pragma unroll
      for (int cc = 0; cc < 2; ++cc) {
        bf16x8 kv = __builtin_bit_cast(bf16x8, kf[t2][cc]);
        acc = __builtin_amdgcn_mfma_f32_16x16x32_bf16(
            kv, __builtin_bit_cast(bf16x8, qh[cc]), acc, 0, 0, 0);
        acc = __builtin_amdgcn_mfma_f32_16x16x32_bf16(
            kv, __builtin_bit_cast(bf16x8, ql[cc]), acc, 0, 0, 0);
      }
      accs[tgb * 4 + t2] = acc;
    }
  }

  // ---- mask (precomputed f16) + causal + max
  const float* posb = pos + b * LN;
  const float plr = posb[l];
  const _Float16* mrow = mw + ((size_t)h * LN + l) * SN;

  float mx = -3.0e38f;
#pragma unroll
  for (int tg = 0; tg < 16; ++tg) {
    const int s0 = w * 256 + tg * 16 + cg * 4;
    f16x4 m4 = *(const f16x4*)(mrow + s0);
    float4 po4 = *(const float4*)(posb + s0);
    float pov[4] = {po4.x, po4.y, po4.z, po4.w};
#pragma unroll
    for (int r = 0; r < 4; ++r) {
      float v = fmaf(accs[tg][r], 0.125f, (float)m4[r]);
      bool maskd = (causal != 0) && (pov[r] > plr);
      v = maskd ? -1.0e30f : v;
      accs[tg][r] = v;
      mx = fmaxf(mx, v);
    }
  }
  mx = fmaxf(mx, __shfl_xor(mx, 16, 64));
  mx = fmaxf(mx, __shfl_xor(mx, 32, 64));
  if (cg == 0) red0[w][cl] = mx;
  __syncthreads();
  const float bmx = fmaxf(fmaxf(red0[0][cl], red0[1][cl]),
                          fmaxf(red0[2][cl], red0[3][cl]));

  float zz = 0.f, ee = 0.f;
#pragma unroll
  for (int tg = 0; tg < 16; ++tg) {
#pragma unroll
    for (int r = 0; r < 4; ++r) {
      float tt = accs[tg][r] - bmx;
      float ex = __expf(tt);
      zz += ex;
      ee = fmaf(ex, fmaxf(tt, -88.0f), ee);  // guard 0 * -1e30
      accs[tg][r] = ex;
    }
  }
  zz += __shfl_xor(zz, 16, 64);
  zz += __shfl_xor(zz, 32, 64);
  ee += __shfl_xor(ee, 16, 64);
  ee += __shfl_xor(ee, 32, 64);
  if (cg == 0) { redZ[w][cl] = zz; redE[w][cl] = ee; }
  __syncthreads();
  const float Z = redZ[0][cl] + redZ[1][cl] + redZ[2][cl] + redZ[3][cl];
  const float E = redE[0][cl] + redE[1][cl] + redE[2][cl] + redE[3][cl];
  const float rz = __fdividef(1.0f, Z);

  // ---- normalized bf16 att into LDS (pitch 2064, linear within row)
  unsigned char* arow = lds_att + cl * APITCH;
#pragma unroll
  for (int tg = 0; tg < 16; ++tg) {
    const int s0 = w * 256 + tg * 16 + cg * 4;
    float ax = accs[tg][0] * rz, ay = accs[tg][1] * rz;
    float az = accs[tg][2] * rz, aw = accs[tg][3] * rz;
    uint2v pk = uint2v{
        (__float_as_uint(ax) >> 16) | (__float_as_uint(ay) & 0xffff0000u),
        (__float_as_uint(az) >> 16) | (__float_as_uint(aw) & 0xffff0000u)};
    *(uint2v*)(arow + s0 * 2) = pk;
  }
  if (w == 0 && cg == 0)
    out[OFF_ENT + ((size_t)b * HN + h) * LN + l] = __logf(Z) - E * rz;

  __syncthreads();  // full att tile visible

  // ---- coalesced fp32 att write: wave w -> rows w*4..w*4+3
  {
    float* abase = out + OFF_ATT + (((size_t)b * HN + h) * LN + lb * 16) * SN;
#pragma unroll
    for (int rr = 0; rr < 4; ++rr) {
      const int row = w * 4 + rr;
      const unsigned char* src = lds_att + row * APITCH;
      float* dst = abase + (size_t)row * SN;
#pragma unroll
      for (int it = 0; it < 4; ++it) {
        uint2v pk = *(const uint2v*)(src + it * 512 + c * 8);
        float4 o = float4{__uint_as_float(pk.x << 16),
                          __uint_as_float(pk.x & 0xffff0000u),
                          __uint_as_float(pk.y << 16),
                          __uint_as_float(pk.y & 0xffff0000u)};
        *(float4*)(dst + it * 256 + c * 4) = o;
      }
    }
  }

  // ---- e-split PV: wave w owns e in [w*16, w*16+16).
  // A = vT frag (m = e-local = cl, k = cg*8+j), B = att LDS frag (n = cl,
  // k = cg*8+j). 32 chunks of 32 s, alternating acc chains.
  const unsigned short* vbb =
      vT + ((size_t)(b * 8 + h) * 64 + w * 16 + cl) * 1024;
  f32x4 acc0 = f32x4{0.f, 0.f, 0.f, 0.f};
  f32x4 acc1 = f32x4{0.f, 0.f, 0.f, 0.f};
#pragma unroll
  for (int scb = 0; scb < 8; ++scb) {
    uint4v vf[4], af[4];
#pragma unroll
    for (int j = 0; j < 4; ++j) {
      const int sc = scb * 4 + j;
      vf[j] = *(const uint4v*)(vbb + sc * 32 + cg * 8);
      af[j] = *(const uint4v*)(lds_att + cl * APITCH + sc * 64 + cg * 16);
    }
#pragma unroll
    for (int j = 0; j < 4; ++j) {
      bf16x8 a8 = __builtin_bit_cast(bf16x8, vf[j]);
      bf16x8 b8 = __builtin_bit_cast(bf16x8, af[j]);
      if (j & 1)
        acc1 = __builtin_amdgcn_mfma_f32_16x16x32_bf16(a8, b8, acc1, 0, 0, 0);
      else
        acc0 = __builtin_amdgcn_mfma_f32_16x16x32_bf16(a8, b8, acc0, 0, 0, 0);
    }
  }
  f32x4 sum = acc0 + acc1;
  // D: col = cl = q-row, row = cg*4+r = e-local -> 4 contiguous e per lane
  *(f32x4*)(out + (((size_t)b * LN + l) * HN + h) * EN + w * 16 + cg * 4) = sum;
}

extern "C" void kernel_launch(void* const* d_in, const int* in_sizes, int n_in,
                              void* d_out, int out_size, void* d_ws, size_t ws_size,
                              hipStream_t stream) {
  (void)in_sizes; (void)n_in; (void)out_size; (void)ws_size;
  const float* q   = (const float*)d_in[0];
  const float* k   = (const float*)d_in[1];
  const float* v   = (const float*)d_in[2];
  const float* pos = (const float*)d_in[3];
  const float* phi = (const float*)d_in[4];
  const float* u   = (const float*)d_in[5];
  const float* lt  = (const float*)d_in[6];
  const float* th  = (const float*)d_in[7];
  const int*   cm  = (const int*)d_in[8];
  float* out = (float*)d_out;

  _Float16* mw = (_Float16*)((char*)d_ws + WS_MW);
  unsigned short* kb = (unsigned short*)((char*)d_ws + WS_KB);
  unsigned short* vT = (unsigned short*)((char*)d_ws + WS_VT);

  dim3 blk(256, 1, 1);
  k_mask_prep<<<dim3(8192), blk, 0, stream>>>(phi, u, lt, th, mw);
  k_kprep<<<dim3(1024), blk, 0, stream>>>(k, kb);
  k_vprep<<<dim3(1024), blk, 0, stream>>>(v, vT);
  k_fused<<<dim3(256, 8, 1), blk, 0, stream>>>(q, kb, vT, mw, pos, cm, out);
}

// Round 8
// 132.509 us; speedup vs baseline: 1.8932x; 1.1901x over previous
//
#include <hip/hip_runtime.h>

#define BN 4
#define LN 1024
#define SN 1024
#define HN 8
#define EN 64
#define OFF_ATT (BN * LN * HN * EN)
#define OFF_ENT (OFF_ATT + BN * HN * LN * SN)

// workspace byte offsets (need ~25 MB)
#define WS_MW 0u                          // f16 mask, 8*1024*1024*2 = 16 MB
#define WS_KB 16777216u                   // bf16 K, 4 MB
#define WS_VT (WS_KB + 4194304u)          // bf16 V^T, 4 MB

// att/mask LDS tile: 16 rows, pitch 2064 B
#define APITCH 2064

typedef __attribute__((ext_vector_type(8))) __bf16 bf16x8;
typedef __attribute__((ext_vector_type(4))) float f32x4;
typedef __attribute__((ext_vector_type(4))) unsigned int uint4v;
typedef __attribute__((ext_vector_type(2))) unsigned int uint2v;
typedef __attribute__((ext_vector_type(4))) _Float16 f16x4;

// blockIdx.x encodes (lbHi, b, lbLo): batch-siblings of an (h,l-tile) are 8
// blocks apart -> same XCD under round-robin -> shared mw slices L2-hot.
__device__ __forceinline__ void decode_block(int x, int& b, int& lb) {
  int lbLo = x & 7;
  b = (x >> 3) & 3;
  lb = (x >> 5) * 8 + lbLo;
}

// 8 consecutive floats -> packed bf16 hi + lo (trunc split)
__device__ __forceinline__ void cvt8(const float* p, uint4v& hv, uint4v& lv) {
  float4 a = *(const float4*)p;
  float4 bq = *(const float4*)(p + 4);
  float x[8] = {a.x, a.y, a.z, a.w, bq.x, bq.y, bq.z, bq.w};
  unsigned int h[8], lo[8];
#pragma unroll
  for (int i = 0; i < 8; ++i) {
    unsigned int ub = __float_as_uint(x[i]);
    h[i] = ub >> 16;
    float lf = x[i] - __uint_as_float(ub & 0xffff0000u);
    lo[i] = __float_as_uint(lf) >> 16;
  }
  hv = uint4v{h[0] | (h[1] << 16), h[2] | (h[3] << 16),
              h[4] | (h[5] << 16), h[6] | (h[7] << 16)};
  lv = uint4v{lo[0] | (lo[1] << 16), lo[2] | (lo[3] << 16),
              lo[4] | (lo[5] << 16), lo[6] | (lo[7] << 16)};
}

__device__ __forceinline__ uint4v pack8_trunc(float4 a, float4 b) {
  return uint4v{(__float_as_uint(a.x) >> 16) | (__float_as_uint(a.y) & 0xffff0000u),
                (__float_as_uint(a.z) >> 16) | (__float_as_uint(a.w) & 0xffff0000u),
                (__float_as_uint(b.x) >> 16) | (__float_as_uint(b.y) & 0xffff0000u),
                (__float_as_uint(b.z) >> 16) | (__float_as_uint(b.w) & 0xffff0000u)};
}

// ---------------- prep kernels ----------------

// phi-mask (f16): pm = -10000*relu(thr - sigmoid((gumbel+phi)/tau)) * 0.125
__global__ __launch_bounds__(256) void k_mask_prep(
    const float* __restrict__ phi, const float* __restrict__ u,
    const float* __restrict__ p_logtau, const float* __restrict__ p_thresh,
    _Float16* __restrict__ mw) {
  const float tau = fminf(fmaxf(__expf(p_logtau[0]), 0.1f), 5.0f);
  const float rtau = 1.0f / tau;
  const float thr = fminf(fmaxf(p_thresh[0], 0.01f), 0.99f);
  int idx = (blockIdx.x * 256 + threadIdx.x) * 4;
  float4 u4 = *(const float4*)(u + idx);
  float4 p4 = *(const float4*)(phi + idx);
  float uu[4] = {u4.x, u4.y, u4.z, u4.w};
  float pp[4] = {p4.x, p4.y, p4.z, p4.w};
  f16x4 o;
#pragma unroll
  for (int i = 0; i < 4; ++i) {
    float g = __logf(__fdividef(uu[i] + 1e-8f, 1.0f - uu[i] + 1e-8f));
    float z = (g + pp[i]) * rtau;
    float sig = __fdividef(1.0f, 1.0f + __expf(-z));
    o[i] = (_Float16)(-10000.0f * fmaxf(thr - sig, 0.0f) * 0.125f);
  }
  *(f16x4*)(mw + idx) = o;
}

// K [b,s,h,e] fp32 -> kb [b][h][s][e] bf16 (single, truncation)
__global__ __launch_bounds__(256) void k_kprep(const float* __restrict__ kk,
                                               unsigned short* __restrict__ kb) {
  int gid = blockIdx.x * 256 + threadIdx.x;
  int e8 = gid & 7;
  int tmp = gid >> 3;
  int h = tmp & 7;
  int bs = tmp >> 3;
  int s = bs & 1023;
  int b = bs >> 10;
  const float* src = kk + (size_t)gid * 8;
  float4 a = *(const float4*)src;
  float4 bq = *(const float4*)(src + 4);
  *(uint4v*)(kb + (((size_t)(b * 8 + h) * 1024 + s) * 64) + e8 * 8) =
      pack8_trunc(a, bq);
}

// V [b,s,h,e] fp32 -> vT [b][h][e][s] bf16 (transpose)
__global__ __launch_bounds__(256) void k_vprep(const float* __restrict__ vv,
                                               unsigned short* __restrict__ vT) {
  int gid = blockIdx.x * 256 + threadIdx.x;
  int s8 = gid & 127;
  int t1 = gid >> 7;
  int e = t1 & 63;
  int t2 = t1 >> 6;
  int h = t2 & 7;
  int b = t2 >> 3;
  float x[8];
#pragma unroll
  for (int j = 0; j < 8; ++j)
    x[j] = vv[((size_t)(b * 1024 + s8 * 8 + j) * 8 + h) * 64 + e];
  uint4v pv = pack8_trunc(float4{x[0], x[1], x[2], x[3]},
                          float4{x[4], x[5], x[6], x[7]});
  *(uint4v*)(vT + ((size_t)(b * 8 + h) * 64 + e) * 1024 + s8 * 8) = pv;
}

// ---------------- fused scores + mask + softmax + entropy + PV ----------------
// Block = 4 waves, 16 q-rows of one (b,h). Swapped QK^T (D = K*Q): lane
// (cl,cg) owns q-row l=lb*16+cl, s = w*256 + tg*16 + cg*4..+3.
// Phase 0: stage mask (32KB) + pos (4KB) into LDS (one deep load batch, then
// consumed latency-free after QK). Mask shares the att LDS buffer (mask reads
// finish before bar2; att writes start after). After softmax, normalized
// bf16 att tile in LDS; coalesced fp32 att write; e-split PV (wave w owns
// e-slice w, full s-sum, no cross-wave reduce), 8-deep load batches.
__global__ __launch_bounds__(256, 4) void k_fused(
    const float* __restrict__ q, const unsigned short* __restrict__ kb,
    const unsigned short* __restrict__ vT, const _Float16* __restrict__ mw,
    const float* __restrict__ pos, const int* __restrict__ p_causal,
    float* __restrict__ out) {
  int b, lb;
  decode_block(blockIdx.x, b, lb);
  const int h = blockIdx.y;
  const int tid = threadIdx.x;
  const int w = __builtin_amdgcn_readfirstlane(tid >> 6);
  const int c = tid & 63;
  const int cl = c & 15;
  const int cg = c >> 4;

  __shared__ __align__(16) unsigned char lds_att[16 * APITCH];
  __shared__ __align__(16) float lds_pos[1024];
  __shared__ float red0[4][16], redZ[4][16], redE[4][16];

  const int causal = p_causal[0];
  const int l = lb * 16 + cl;  // this lane's q-row
  const float* posb = pos + b * LN;

  // ---- phase 0: stage mask + pos into LDS (one deep VMEM batch)
  {
    const unsigned char* gmask =
        (const unsigned char*)(mw + ((size_t)h * LN + lb * 16) * SN);
    uint4v mk[8];
#pragma unroll
    for (int i = 0; i < 8; ++i)
      mk[i] = *(const uint4v*)(gmask + i * 4096 + tid * 16);
    float4 pv4 = *(const float4*)(posb + tid * 4);
#pragma unroll
    for (int i = 0; i < 8; ++i) {
      int goff = i * 4096 + tid * 16;
      *(uint4v*)(lds_att + (goff >> 11) * APITCH + (goff & 2047)) = mk[i];
    }
    *(float4*)(lds_pos + tid * 4) = pv4;
  }

  // Q fragments (B operand): n = cl (q-row), k = cg*8+j within 32-chunk
  uint4v qh[2], ql[2];
#pragma unroll
  for (int cc = 0; cc < 2; ++cc) {
    const float* qp = q + (((size_t)b * LN + l) * HN + h) * EN + cc * 32 + cg * 8;
    cvt8(qp, qh[cc], ql[cc]);
  }

  __syncthreads();  // staging visible (placed before QK: no added stall)

  const unsigned short* kbb = kb + ((size_t)(b * 8 + h) * 1024) * 64;
  f32x4 accs[16];

  // ---- QK^T: batches of 4 tiles -> 8 loads in flight, then 16 MFMAs
#pragma unroll
  for (int tgb = 0; tgb < 4; ++tgb) {
    uint4v kf[4][2];
#pragma unroll
    for (int t2 = 0; t2 < 4; ++t2) {
      const int row = w * 256 + (tgb * 4 + t2) * 16 + cl;
#pragma unroll
      for (int cc = 0; cc < 2; ++cc)
        kf[t2][cc] = *(const uint4v*)(kbb + (size_t)row * 64 + cc * 32 + cg * 8);
    }
#pragma unroll
    for (int t2 = 0; t2 < 4; ++t2) {
      f32x4 acc = f32x4{0.f, 0.f, 0.f, 0.f};
#pragma unroll
      for (int cc = 0; cc < 2; ++cc) {
        bf16x8 kv = __builtin_bit_cast(bf16x8, kf[t2][cc]);
        acc = __builtin_amdgcn_mfma_f32_16x16x32_bf16(
            kv, __builtin_bit_cast(bf16x8, qh[cc]), acc, 0, 0, 0);
        acc = __builtin_amdgcn_mfma_f32_16x16x32_bf16(
            kv, __builtin_bit_cast(bf16x8, ql[cc]), acc, 0, 0, 0);
      }
      accs[tgb * 4 + t2] = acc;
    }
  }

  // ---- mask (LDS f16) + causal (LDS pos) + max — zero global VMEM
  const float plr = lds_pos[l];
  const unsigned char* mbase = lds_att + cl * APITCH;

  float mx = -3.0e38f;
#pragma unroll
  for (int tg = 0; tg < 16; ++tg) {
    const int s0 = w * 256 + tg * 16 + cg * 4;
    f16x4 m4 = *(const f16x4*)(mbase + s0 * 2);
    float4 po4 = *(const float4*)(lds_pos + s0);
    float pov[4] = {po4.x, po4.y, po4.z, po4.w};
#pragma unroll
    for (int r = 0; r < 4; ++r) {
      float v = fmaf(accs[tg][r], 0.125f, (float)m4[r]);
      bool maskd = (causal != 0) && (pov[r] > plr);
      v = maskd ? -1.0e30f : v;
      accs[tg][r] = v;
      mx = fmaxf(mx, v);
    }
  }
  mx = fmaxf(mx, __shfl_xor(mx, 16, 64));
  mx = fmaxf(mx, __shfl_xor(mx, 32, 64));
  if (cg == 0) red0[w][cl] = mx;
  __syncthreads();
  const float bmx = fmaxf(fmaxf(red0[0][cl], red0[1][cl]),
                          fmaxf(red0[2][cl], red0[3][cl]));

  float zz = 0.f, ee = 0.f;
#pragma unroll
  for (int tg = 0; tg < 16; ++tg) {
#pragma unroll
    for (int r = 0; r < 4; ++r) {
      float tt = accs[tg][r] - bmx;
      float ex = __expf(tt);
      zz += ex;
      ee = fmaf(ex, fmaxf(tt, -88.0f), ee);  // guard 0 * -1e30
      accs[tg][r] = ex;
    }
  }
  zz += __shfl_xor(zz, 16, 64);
  zz += __shfl_xor(zz, 32, 64);
  ee += __shfl_xor(ee, 16, 64);
  ee += __shfl_xor(ee, 32, 64);
  if (cg == 0) { redZ[w][cl] = zz; redE[w][cl] = ee; }
  __syncthreads();
  const float Z = redZ[0][cl] + redZ[1][cl] + redZ[2][cl] + redZ[3][cl];
  const float E = redE[0][cl] + redE[1][cl] + redE[2][cl] + redE[3][cl];
  const float rz = __fdividef(1.0f, Z);

  // ---- normalized bf16 att into LDS (overwrites mask region; safe post-bar2)
  unsigned char* arow = lds_att + cl * APITCH;
#pragma unroll
  for (int tg = 0; tg < 16; ++tg) {
    const int s0 = w * 256 + tg * 16 + cg * 4;
    float ax = accs[tg][0] * rz, ay = accs[tg][1] * rz;
    float az = accs[tg][2] * rz, aw = accs[tg][3] * rz;
    uint2v pk = uint2v{
        (__float_as_uint(ax) >> 16) | (__float_as_uint(ay) & 0xffff0000u),
        (__float_as_uint(az) >> 16) | (__float_as_uint(aw) & 0xffff0000u)};
    *(uint2v*)(arow + s0 * 2) = pk;
  }
  if (w == 0 && cg == 0)
    out[OFF_ENT + ((size_t)b * HN + h) * LN + l] = __logf(Z) - E * rz;

  __syncthreads();  // full att tile visible

  // ---- coalesced fp32 att write: wave w -> rows w*4..w*4+3
  {
    float* abase = out + OFF_ATT + (((size_t)b * HN + h) * LN + lb * 16) * SN;
#pragma unroll
    for (int rr = 0; rr < 4; ++rr) {
      const int row = w * 4 + rr;
      const unsigned char* src = lds_att + row * APITCH;
      float* dst = abase + (size_t)row * SN;
#pragma unroll
      for (int it = 0; it < 4; ++it) {
        uint2v pk = *(const uint2v*)(src + it * 512 + c * 8);
        float4 o = float4{__uint_as_float(pk.x << 16),
                          __uint_as_float(pk.x & 0xffff0000u),
                          __uint_as_float(pk.y << 16),
                          __uint_as_float(pk.y & 0xffff0000u)};
        *(float4*)(dst + it * 256 + c * 4) = o;
      }
    }
  }

  // ---- e-split PV: wave w owns e in [w*16, w*16+16). 8-deep load batches.
  // A = vT frag (m = e-local = cl, k = cg*8+j), B = att LDS frag (n = cl,
  // k = cg*8+j).
  const unsigned short* vbb =
      vT + ((size_t)(b * 8 + h) * 64 + w * 16 + cl) * 1024;
  f32x4 acc0 = f32x4{0.f, 0.f, 0.f, 0.f};
  f32x4 acc1 = f32x4{0.f, 0.f, 0.f, 0.f};
#pragma unroll
  for (int scb = 0; scb < 4; ++scb) {
    uint4v vf[8], af[8];
#pragma unroll
    for (int j = 0; j < 8; ++j) {
      const int sc = scb * 8 + j;
      vf[j] = *(const uint4v*)(vbb + sc * 32 + cg * 8);
      af[j] = *(const uint4v*)(lds_att + cl * APITCH + sc * 64 + cg * 16);
    }
#pragma unroll
    for (int j = 0; j < 8; ++j) {
      bf16x8 a8 = __builtin_bit_cast(bf16x8, vf[j]);
      bf16x8 b8 = __builtin_bit_cast(bf16x8, af[j]);
      if (j & 1)
        acc1 = __builtin_amdgcn_mfma_f32_16x16x32_bf16(a8, b8, acc1, 0, 0, 0);
      else
        acc0 = __builtin_amdgcn_mfma_f32_16x16x32_bf16(a8, b8, acc0, 0, 0, 0);
    }
  }
  f32x4 sum = acc0 + acc1;
  // D: col = cl = q-row, row = cg*4+r = e-local -> 4 contiguous e per lane
  *(f32x4*)(out + (((size_t)b * LN + l) * HN + h) * EN + w * 16 + cg * 4) = sum;
}

extern "C" void kernel_launch(void* const* d_in, const int* in_sizes, int n_in,
                              void* d_out, int out_size, void* d_ws, size_t ws_size,
                              hipStream_t stream) {
  (void)in_sizes; (void)n_in; (void)out_size; (void)ws_size;
  const float* q   = (const float*)d_in[0];
  const float* k   = (const float*)d_in[1];
  const float* v   = (const float*)d_in[2];
  const float* pos = (const float*)d_in[3];
  const float* phi = (const float*)d_in[4];
  const float* u   = (const float*)d_in[5];
  const float* lt  = (const float*)d_in[6];
  const float* th  = (const float*)d_in[7];
  const int*   cm  = (const int*)d_in[8];
  float* out = (float*)d_out;

  _Float16* mw = (_Float16*)((char*)d_ws + WS_MW);
  unsigned short* kb = (unsigned short*)((char*)d_ws + WS_KB);
  unsigned short* vT = (unsigned short*)((char*)d_ws + WS_VT);

  dim3 blk(256, 1, 1);
  k_mask_prep<<<dim3(8192), blk, 0, stream>>>(phi, u, lt, th, mw);
  k_kprep<<<dim3(1024), blk, 0, stream>>>(k, kb);
  k_vprep<<<dim3(1024), blk, 0, stream>>>(v, vT);
  k_fused<<<dim3(256, 8, 1), blk, 0, stream>>>(q, kb, vT, mw, pos, cm, out);
}

// Round 10
// 117.963 us; speedup vs baseline: 2.1267x; 1.1233x over previous
//
#include <hip/hip_runtime.h>

#define BN 4
#define LN 1024
#define SN 1024
#define HN 8
#define EN 64
#define OFF_ATT (BN * LN * HN * EN)
#define OFF_ENT (OFF_ATT + BN * HN * LN * SN)

// workspace byte offsets (need ~25 MB)
#define WS_MW 0u                          // f16 mask, 8*1024*1024*2 = 16 MB
#define WS_KB 16777216u                   // bf16 K, 4 MB
#define WS_VT (WS_KB + 4194304u)          // bf16 V^T, 4 MB

// att/mask LDS tile: 16 rows, pitch 2064 B
#define APITCH 2064

typedef __attribute__((ext_vector_type(8))) __bf16 bf16x8;
typedef __attribute__((ext_vector_type(4))) float f32x4;
typedef __attribute__((ext_vector_type(4))) unsigned int uint4v;
typedef __attribute__((ext_vector_type(2))) unsigned int uint2v;
typedef __attribute__((ext_vector_type(4))) _Float16 f16x4;

// blockIdx.x encodes (lbHi, b, lbLo): batch-siblings of an (h,l-tile) are 8
// blocks apart -> same XCD under round-robin -> shared mw slices L2-hot.
__device__ __forceinline__ void decode_block(int x, int& b, int& lb) {
  int lbLo = x & 7;
  b = (x >> 3) & 3;
  lb = (x >> 5) * 8 + lbLo;
}

// 8 consecutive floats -> packed bf16 hi + lo (trunc split)
__device__ __forceinline__ void cvt8(const float* p, uint4v& hv, uint4v& lv) {
  float4 a = *(const float4*)p;
  float4 bq = *(const float4*)(p + 4);
  float x[8] = {a.x, a.y, a.z, a.w, bq.x, bq.y, bq.z, bq.w};
  unsigned int h[8], lo[8];
#pragma unroll
  for (int i = 0; i < 8; ++i) {
    unsigned int ub = __float_as_uint(x[i]);
    h[i] = ub >> 16;
    float lf = x[i] - __uint_as_float(ub & 0xffff0000u);
    lo[i] = __float_as_uint(lf) >> 16;
  }
  hv = uint4v{h[0] | (h[1] << 16), h[2] | (h[3] << 16),
              h[4] | (h[5] << 16), h[6] | (h[7] << 16)};
  lv = uint4v{lo[0] | (lo[1] << 16), lo[2] | (lo[3] << 16),
              lo[4] | (lo[5] << 16), lo[6] | (lo[7] << 16)};
}

__device__ __forceinline__ uint4v pack8_trunc(float4 a, float4 b) {
  return uint4v{(__float_as_uint(a.x) >> 16) | (__float_as_uint(a.y) & 0xffff0000u),
                (__float_as_uint(a.z) >> 16) | (__float_as_uint(a.w) & 0xffff0000u),
                (__float_as_uint(b.x) >> 16) | (__float_as_uint(b.y) & 0xffff0000u),
                (__float_as_uint(b.z) >> 16) | (__float_as_uint(b.w) & 0xffff0000u)};
}

// ---------------- prep kernels ----------------

// phi-mask (f16): pm = -10000*relu(thr - sigmoid((gumbel+phi)/tau)) * 0.125
__global__ __launch_bounds__(256) void k_mask_prep(
    const float* __restrict__ phi, const float* __restrict__ u,
    const float* __restrict__ p_logtau, const float* __restrict__ p_thresh,
    _Float16* __restrict__ mw) {
  const float tau = fminf(fmaxf(__expf(p_logtau[0]), 0.1f), 5.0f);
  const float rtau = 1.0f / tau;
  const float thr = fminf(fmaxf(p_thresh[0], 0.01f), 0.99f);
  int idx = (blockIdx.x * 256 + threadIdx.x) * 4;
  float4 u4 = *(const float4*)(u + idx);
  float4 p4 = *(const float4*)(phi + idx);
  float uu[4] = {u4.x, u4.y, u4.z, u4.w};
  float pp[4] = {p4.x, p4.y, p4.z, p4.w};
  f16x4 o;
#pragma unroll
  for (int i = 0; i < 4; ++i) {
    float g = __logf(__fdividef(uu[i] + 1e-8f, 1.0f - uu[i] + 1e-8f));
    float z = (g + pp[i]) * rtau;
    float sig = __fdividef(1.0f, 1.0f + __expf(-z));
    o[i] = (_Float16)(-10000.0f * fmaxf(thr - sig, 0.0f) * 0.125f);
  }
  *(f16x4*)(mw + idx) = o;
}

// K [b,s,h,e] fp32 -> kb [b][h][s][e] bf16 (single, truncation)
__global__ __launch_bounds__(256) void k_kprep(const float* __restrict__ kk,
                                               unsigned short* __restrict__ kb) {
  int gid = blockIdx.x * 256 + threadIdx.x;
  int e8 = gid & 7;
  int tmp = gid >> 3;
  int h = tmp & 7;
  int bs = tmp >> 3;
  int s = bs & 1023;
  int b = bs >> 10;
  const float* src = kk + (size_t)gid * 8;
  float4 a = *(const float4*)src;
  float4 bq = *(const float4*)(src + 4);
  *(uint4v*)(kb + (((size_t)(b * 8 + h) * 1024 + s) * 64) + e8 * 8) =
      pack8_trunc(a, bq);
}

// V [b,s,h,e] fp32 -> vT [b][h][e][s] bf16 (transpose)
__global__ __launch_bounds__(256) void k_vprep(const float* __restrict__ vv,
                                               unsigned short* __restrict__ vT) {
  int gid = blockIdx.x * 256 + threadIdx.x;
  int s8 = gid & 127;
  int t1 = gid >> 7;
  int e = t1 & 63;
  int t2 = t1 >> 6;
  int h = t2 & 7;
  int b = t2 >> 3;
  float x[8];
#pragma unroll
  for (int j = 0; j < 8; ++j)
    x[j] = vv[((size_t)(b * 1024 + s8 * 8 + j) * 8 + h) * 64 + e];
  uint4v pv = pack8_trunc(float4{x[0], x[1], x[2], x[3]},
                          float4{x[4], x[5], x[6], x[7]});
  *(uint4v*)(vT + ((size_t)(b * 8 + h) * 64 + e) * 1024 + s8 * 8) = pv;
}

// ---------------- fused scores + mask + softmax + entropy + PV ----------------
// Block = 8 waves (512 thr), 16 q-rows of one (b,h). Swapped QK^T (D = K*Q):
// lane (cl,cg) of wave w owns q-row l=lb*16+cl, s = w*128 + tg*16 + cg*4..+3
// (wave w owns s-range [w*128, w*128+128) -> accs[8], 32 AGPR: 2x waves/CU
// vs the 16-tile version). Phase 0: stage mask (32KB) + pos (4KB) into LDS.
// After softmax, normalized bf16 att tile in LDS; coalesced nontemporal fp32
// att write; PV split e(4) x s-half(2) across the 8 waves, partial reduce
// through reused att LDS, coalesced nontemporal V write.
__global__ __launch_bounds__(512, 5) void k_fused(
    const float* __restrict__ q, const unsigned short* __restrict__ kb,
    const unsigned short* __restrict__ vT, const _Float16* __restrict__ mw,
    const float* __restrict__ pos, const int* __restrict__ p_causal,
    float* __restrict__ out) {
  int b, lb;
  decode_block(blockIdx.x, b, lb);
  const int h = blockIdx.y;
  const int tid = threadIdx.x;
  const int w = __builtin_amdgcn_readfirstlane(tid >> 6);  // 0..7
  const int c = tid & 63;
  const int cl = c & 15;
  const int cg = c >> 4;

  __shared__ __align__(16) unsigned char lds_att[16 * APITCH];
  __shared__ __align__(16) float lds_pos[1024];
  __shared__ float red0[8][16], redZ[8][16], redE[8][16];

  const int causal = p_causal[0];
  const int l = lb * 16 + cl;  // this lane's q-row
  const float* posb = pos + b * LN;

  // ---- phase 0: stage mask + pos into LDS (one deep VMEM batch)
  {
    const unsigned char* gmask =
        (const unsigned char*)(mw + ((size_t)h * LN + lb * 16) * SN);
    uint4v mk[4];
#pragma unroll
    for (int i = 0; i < 4; ++i)
      mk[i] = *(const uint4v*)(gmask + i * 8192 + tid * 16);
    float4 pv4;
    if (tid < 256) pv4 = *(const float4*)(posb + tid * 4);
#pragma unroll
    for (int i = 0; i < 4; ++i) {
      int goff = i * 8192 + tid * 16;
      *(uint4v*)(lds_att + (goff >> 11) * APITCH + (goff & 2047)) = mk[i];
    }
    if (tid < 256) *(float4*)(lds_pos + tid * 4) = pv4;
  }

  // Q fragments (B operand): n = cl (q-row), k = cg*8+j within 32-chunk
  uint4v qh[2], ql[2];
#pragma unroll
  for (int cc = 0; cc < 2; ++cc) {
    const float* qp = q + (((size_t)b * LN + l) * HN + h) * EN + cc * 32 + cg * 8;
    cvt8(qp, qh[cc], ql[cc]);
  }

  __syncthreads();  // staging visible

  const unsigned short* kbb = kb + ((size_t)(b * 8 + h) * 1024) * 64;
  f32x4 accs[8];

  // ---- QK^T: 2 batches of 4 tiles (8 loads in flight, then 16 MFMAs)
#pragma unroll
  for (int tgb = 0; tgb < 2; ++tgb) {
    uint4v kf[4][2];
#pragma unroll
    for (int t2 = 0; t2 < 4; ++t2) {
      const int row = w * 128 + (tgb * 4 + t2) * 16 + cl;
#pragma unroll
      for (int cc = 0; cc < 2; ++cc)
        kf[t2][cc] = *(const uint4v*)(kbb + (size_t)row * 64 + cc * 32 + cg * 8);
    }
#pragma unroll
    for (int t2 = 0; t2 < 4; ++t2) {
      f32x4 acc = f32x4{0.f, 0.f, 0.f, 0.f};
#pragma unroll
      for (int cc = 0; cc < 2; ++cc) {
        bf16x8 kv = __builtin_bit_cast(bf16x8, kf[t2][cc]);
        acc = __builtin_amdgcn_mfma_f32_16x16x32_bf16(
            kv, __builtin_bit_cast(bf16x8, qh[cc]), acc, 0, 0, 0);
        acc = __builtin_amdgcn_mfma_f32_16x16x32_bf16(
            kv, __builtin_bit_cast(bf16x8, ql[cc]), acc, 0, 0, 0);
      }
      accs[tgb * 4 + t2] = acc;
    }
  }

  // ---- mask (LDS f16) + causal (LDS pos) + max — zero global VMEM
  const float plr = lds_pos[l];
  const unsigned char* mbase = lds_att + cl * APITCH;

  float mx = -3.0e38f;
#pragma unroll
  for (int tg = 0; tg < 8; ++tg) {
    const int s0 = w * 128 + tg * 16 + cg * 4;
    f16x4 m4 = *(const f16x4*)(mbase + s0 * 2);
    float4 po4 = *(const float4*)(lds_pos + s0);
    float pov[4] = {po4.x, po4.y, po4.z, po4.w};
#pragma unroll
    for (int r = 0; r < 4; ++r) {
      float v = fmaf(accs[tg][r], 0.125f, (float)m4[r]);
      bool maskd = (causal != 0) && (pov[r] > plr);
      v = maskd ? -1.0e30f : v;
      accs[tg][r] = v;
      mx = fmaxf(mx, v);
    }
  }
  mx = fmaxf(mx, __shfl_xor(mx, 16, 64));
  mx = fmaxf(mx, __shfl_xor(mx, 32, 64));
  if (cg == 0) red0[w][cl] = mx;
  __syncthreads();
  float bmx = red0[0][cl];
#pragma unroll
  for (int i = 1; i < 8; ++i) bmx = fmaxf(bmx, red0[i][cl]);

  float zz = 0.f, ee = 0.f;
#pragma unroll
  for (int tg = 0; tg < 8; ++tg) {
#pragma unroll
    for (int r = 0; r < 4; ++r) {
      float tt = accs[tg][r] - bmx;
      float ex = __expf(tt);
      zz += ex;
      ee = fmaf(ex, fmaxf(tt, -88.0f), ee);  // guard 0 * -1e30
      accs[tg][r] = ex;
    }
  }
  zz += __shfl_xor(zz, 16, 64);
  zz += __shfl_xor(zz, 32, 64);
  ee += __shfl_xor(ee, 16, 64);
  ee += __shfl_xor(ee, 32, 64);
  if (cg == 0) { redZ[w][cl] = zz; redE[w][cl] = ee; }
  __syncthreads();
  float Z = redZ[0][cl], E = redE[0][cl];
#pragma unroll
  for (int i = 1; i < 8; ++i) { Z += redZ[i][cl]; E += redE[i][cl]; }
  const float rz = __fdividef(1.0f, Z);

  // ---- normalized bf16 att into LDS (overwrites mask region; safe post-bar)
  unsigned char* arow = lds_att + cl * APITCH;
#pragma unroll
  for (int tg = 0; tg < 8; ++tg) {
    const int s0 = w * 128 + tg * 16 + cg * 4;
    float ax = accs[tg][0] * rz, ay = accs[tg][1] * rz;
    float az = accs[tg][2] * rz, aw = accs[tg][3] * rz;
    uint2v pk = uint2v{
        (__float_as_uint(ax) >> 16) | (__float_as_uint(ay) & 0xffff0000u),
        (__float_as_uint(az) >> 16) | (__float_as_uint(aw) & 0xffff0000u)};
    *(uint2v*)(arow + s0 * 2) = pk;
  }
  if (w == 0 && cg == 0)
    out[OFF_ENT + ((size_t)b * HN + h) * LN + l] = __logf(Z) - E * rz;

  __syncthreads();  // full att tile visible

  // ---- coalesced nontemporal fp32 att write: wave w -> rows w*2, w*2+1
  {
    float* abase = out + OFF_ATT + (((size_t)b * HN + h) * LN + lb * 16) * SN;
#pragma unroll
    for (int rr = 0; rr < 2; ++rr) {
      const int row = w * 2 + rr;
      const unsigned char* src = lds_att + row * APITCH;
      float* dst = abase + (size_t)row * SN;
#pragma unroll
      for (int it = 0; it < 4; ++it) {
        uint2v pk = *(const uint2v*)(src + it * 512 + c * 8);
        f32x4 o = f32x4{__uint_as_float(pk.x << 16),
                        __uint_as_float(pk.x & 0xffff0000u),
                        __uint_as_float(pk.y << 16),
                        __uint_as_float(pk.y & 0xffff0000u)};
        __builtin_nontemporal_store(o, (f32x4*)(dst + it * 256 + c * 4));
      }
    }
  }

  // ---- PV: wave w -> e-tile (w&3), s-half (w>>2). 2 batches of 8.
  // A = vT frag (m = e-local = cl, k-slice), B = att LDS frag (n = cl).
  const int et = w & 3, sh = w >> 2;
  const unsigned short* vbb =
      vT + ((size_t)(b * 8 + h) * 64 + et * 16 + cl) * 1024 + sh * 512;
  f32x4 acc0 = f32x4{0.f, 0.f, 0.f, 0.f};
  f32x4 acc1 = f32x4{0.f, 0.f, 0.f, 0.f};
#pragma unroll
  for (int scb = 0; scb < 2; ++scb) {
    uint4v vf[8], af[8];
#pragma unroll
    for (int j = 0; j < 8; ++j) {
      const int sc = scb * 8 + j;
      vf[j] = *(const uint4v*)(vbb + sc * 32 + cg * 8);
      af[j] = *(const uint4v*)(lds_att + cl * APITCH +
                               (sh * 512 + sc * 32 + cg * 8) * 2);
    }
#pragma unroll
    for (int j = 0; j < 8; ++j) {
      bf16x8 a8 = __builtin_bit_cast(bf16x8, vf[j]);
      bf16x8 b8 = __builtin_bit_cast(bf16x8, af[j]);
      if (j & 1)
        acc1 = __builtin_amdgcn_mfma_f32_16x16x32_bf16(a8, b8, acc1, 0, 0, 0);
      else
        acc0 = __builtin_amdgcn_mfma_f32_16x16x32_bf16(a8, b8, acc0, 0, 0, 0);
    }
  }
  f32x4 sum = acc0 + acc1;

  // ---- cross s-half reduce via reused att LDS + coalesced V write
  __syncthreads();  // all PV att reads done
  // partial tile w: [q-row cl][e-local cg*4..+3] at w*1024 + cl*64 + cg*16
  *(f32x4*)(lds_att + w * 1024 + cl * 64 + cg * 16) = sum;
  __syncthreads();
  if (tid < 256) {
    const int l_ = tid >> 4, e4 = tid & 15, et_ = e4 >> 2;
    f32x4 p0 = *(const f32x4*)(lds_att + et_ * 1024 + l_ * 64 + (e4 & 3) * 16);
    f32x4 p1 = *(const f32x4*)(lds_att + (et_ + 4) * 1024 + l_ * 64 + (e4 & 3) * 16);
    f32x4 s = p0 + p1;
    float* dst = out + (((size_t)b * LN + lb * 16 + l_) * HN + h) * EN + e4 * 4;
    __builtin_nontemporal_store(s, (f32x4*)dst);
  }
}

extern "C" void kernel_launch(void* const* d_in, const int* in_sizes, int n_in,
                              void* d_out, int out_size, void* d_ws, size_t ws_size,
                              hipStream_t stream) {
  (void)in_sizes; (void)n_in; (void)out_size; (void)ws_size;
  const float* q   = (const float*)d_in[0];
  const float* k   = (const float*)d_in[1];
  const float* v   = (const float*)d_in[2];
  const float* pos = (const float*)d_in[3];
  const float* phi = (const float*)d_in[4];
  const float* u   = (const float*)d_in[5];
  const float* lt  = (const float*)d_in[6];
  const float* th  = (const float*)d_in[7];
  const int*   cm  = (const int*)d_in[8];
  float* out = (float*)d_out;

  _Float16* mw = (_Float16*)((char*)d_ws + WS_MW);
  unsigned short* kb = (unsigned short*)((char*)d_ws + WS_KB);
  unsigned short* vT = (unsigned short*)((char*)d_ws + WS_VT);

  k_mask_prep<<<dim3(8192), dim3(256), 0, stream>>>(phi, u, lt, th, mw);
  k_kprep<<<dim3(1024), dim3(256), 0, stream>>>(k, kb);
  k_vprep<<<dim3(1024), dim3(256), 0, stream>>>(v, vT);
  k_fused<<<dim3(256, 8, 1), dim3(512), 0, stream>>>(q, kb, vT, mw, pos, cm, out);
}

// Round 11
// 113.922 us; speedup vs baseline: 2.2021x; 1.0355x over previous
//
#include <hip/hip_runtime.h>

#define BN 4
#define LN 1024
#define SN 1024
#define HN 8
#define EN 64
#define OFF_ATT (BN * LN * HN * EN)
#define OFF_ENT (OFF_ATT + BN * HN * LN * SN)

// workspace byte offsets (need ~25 MB)
#define WS_MW 0u                          // f16 mask, 8*1024*1024*2 = 16 MB
#define WS_KB 16777216u                   // bf16 K, 4 MB
#define WS_VT (WS_KB + 4194304u)          // bf16 V^T, 4 MB

// att/mask LDS tile: 16 rows, pitch 2064 B
#define APITCH 2064

typedef __attribute__((ext_vector_type(8))) __bf16 bf16x8;
typedef __attribute__((ext_vector_type(4))) float f32x4;
typedef __attribute__((ext_vector_type(4))) unsigned int uint4v;
typedef __attribute__((ext_vector_type(2))) unsigned int uint2v;
typedef __attribute__((ext_vector_type(4))) _Float16 f16x4;

// blockIdx.x encodes (lbHi, b, lbLo): batch-siblings of an (h,l-tile) are 8
// blocks apart -> same XCD under round-robin -> shared mw slices L2-hot.
__device__ __forceinline__ void decode_block(int x, int& b, int& lb) {
  int lbLo = x & 7;
  b = (x >> 3) & 3;
  lb = (x >> 5) * 8 + lbLo;
}

// 8 consecutive floats -> packed bf16 hi + lo (trunc split)
__device__ __forceinline__ void cvt8(const float* p, uint4v& hv, uint4v& lv) {
  float4 a = *(const float4*)p;
  float4 bq = *(const float4*)(p + 4);
  float x[8] = {a.x, a.y, a.z, a.w, bq.x, bq.y, bq.z, bq.w};
  unsigned int h[8], lo[8];
#pragma unroll
  for (int i = 0; i < 8; ++i) {
    unsigned int ub = __float_as_uint(x[i]);
    h[i] = ub >> 16;
    float lf = x[i] - __uint_as_float(ub & 0xffff0000u);
    lo[i] = __float_as_uint(lf) >> 16;
  }
  hv = uint4v{h[0] | (h[1] << 16), h[2] | (h[3] << 16),
              h[4] | (h[5] << 16), h[6] | (h[7] << 16)};
  lv = uint4v{lo[0] | (lo[1] << 16), lo[2] | (lo[3] << 16),
              lo[4] | (lo[5] << 16), lo[6] | (lo[7] << 16)};
}

__device__ __forceinline__ uint4v pack8_trunc(float4 a, float4 b) {
  return uint4v{(__float_as_uint(a.x) >> 16) | (__float_as_uint(a.y) & 0xffff0000u),
                (__float_as_uint(a.z) >> 16) | (__float_as_uint(a.w) & 0xffff0000u),
                (__float_as_uint(b.x) >> 16) | (__float_as_uint(b.y) & 0xffff0000u),
                (__float_as_uint(b.z) >> 16) | (__float_as_uint(b.w) & 0xffff0000u)};
}

// ---------------- fused prep kernel (mask + K + V^T) ----------------
// blocks [0,8192): phi-mask f16; [8192,9216): K->bf16; [9216,10240): V->vT.
__global__ __launch_bounds__(256) void k_prep(
    const float* __restrict__ kk, const float* __restrict__ vv,
    const float* __restrict__ phi, const float* __restrict__ u,
    const float* __restrict__ p_logtau, const float* __restrict__ p_thresh,
    _Float16* __restrict__ mw, unsigned short* __restrict__ kb,
    unsigned short* __restrict__ vT) {
  const int bx = blockIdx.x;
  if (bx < 8192) {
    const float tau = fminf(fmaxf(__expf(p_logtau[0]), 0.1f), 5.0f);
    const float rtau = 1.0f / tau;
    const float thr = fminf(fmaxf(p_thresh[0], 0.01f), 0.99f);
    int idx = (bx * 256 + threadIdx.x) * 4;
    float4 u4 = *(const float4*)(u + idx);
    float4 p4 = *(const float4*)(phi + idx);
    float uu[4] = {u4.x, u4.y, u4.z, u4.w};
    float pp[4] = {p4.x, p4.y, p4.z, p4.w};
    f16x4 o;
#pragma unroll
    for (int i = 0; i < 4; ++i) {
      float g = __logf(__fdividef(uu[i] + 1e-8f, 1.0f - uu[i] + 1e-8f));
      float z = (g + pp[i]) * rtau;
      float sig = __fdividef(1.0f, 1.0f + __expf(-z));
      o[i] = (_Float16)(-10000.0f * fmaxf(thr - sig, 0.0f) * 0.125f);
    }
    *(f16x4*)(mw + idx) = o;
  } else if (bx < 9216) {
    int gid = (bx - 8192) * 256 + threadIdx.x;
    int e8 = gid & 7;
    int tmp = gid >> 3;
    int h = tmp & 7;
    int bs = tmp >> 3;
    int s = bs & 1023;
    int b = bs >> 10;
    const float* src = kk + (size_t)gid * 8;
    float4 a = *(const float4*)src;
    float4 bq = *(const float4*)(src + 4);
    *(uint4v*)(kb + (((size_t)(b * 8 + h) * 1024 + s) * 64) + e8 * 8) =
        pack8_trunc(a, bq);
  } else {
    int gid = (bx - 9216) * 256 + threadIdx.x;
    int s8 = gid & 127;
    int t1 = gid >> 7;
    int e = t1 & 63;
    int t2 = t1 >> 6;
    int h = t2 & 7;
    int b = t2 >> 3;
    float x[8];
#pragma unroll
    for (int j = 0; j < 8; ++j)
      x[j] = vv[((size_t)(b * 1024 + s8 * 8 + j) * 8 + h) * 64 + e];
    uint4v pv = pack8_trunc(float4{x[0], x[1], x[2], x[3]},
                            float4{x[4], x[5], x[6], x[7]});
    *(uint4v*)(vT + ((size_t)(b * 8 + h) * 64 + e) * 1024 + s8 * 8) = pv;
  }
}

// ---------------- fused scores + mask + softmax + entropy + PV ----------------
// Block = 8 waves (512 thr), 16 q-rows of one (b,h). Swapped QK^T (D = K*Q):
// lane (cl,cg) of wave w owns q-row l=lb*16+cl, s = w*128 + tg*16 + cg*4..+3.
// Ordering designed so no barrier drains output stores: all global output
// stores (att fp32, V, entropy) are issued AFTER the last barrier; PV
// partials go to a dedicated LDS buffer so the att tile stays intact.
// Prefetch: K batch-0 issued pre-bar1; vT batch-0 issued pre-bar3.
__global__ __launch_bounds__(512, 4) void k_fused(
    const float* __restrict__ q, const unsigned short* __restrict__ kb,
    const unsigned short* __restrict__ vT, const _Float16* __restrict__ mw,
    const float* __restrict__ pos, const int* __restrict__ p_causal,
    float* __restrict__ out) {
  int b, lb;
  decode_block(blockIdx.x, b, lb);
  const int h = blockIdx.y;
  const int tid = threadIdx.x;
  const int w = __builtin_amdgcn_readfirstlane(tid >> 6);  // 0..7
  const int c = tid & 63;
  const int cl = c & 15;
  const int cg = c >> 4;

  __shared__ __align__(16) unsigned char lds_att[16 * APITCH];
  __shared__ __align__(16) unsigned char lds_part[8192];
  __shared__ __align__(16) float lds_pos[1024];
  __shared__ float red0[8][16], redZ[8][16], redE[8][16];

  const int causal = p_causal[0];
  const int l = lb * 16 + cl;  // this lane's q-row
  const float* posb = pos + b * LN;
  const unsigned short* kbb = kb + ((size_t)(b * 8 + h) * 1024) * 64;

  // ---- phase 0: one deep VMEM batch: mask, pos, Q, K batch-0
  uint4v mk[4];
  {
    const unsigned char* gmask =
        (const unsigned char*)(mw + ((size_t)h * LN + lb * 16) * SN);
#pragma unroll
    for (int i = 0; i < 4; ++i)
      mk[i] = *(const uint4v*)(gmask + i * 8192 + tid * 16);
  }
  float4 pv4;
  if (tid < 256) pv4 = *(const float4*)(posb + tid * 4);
#pragma unroll
  for (int i = 0; i < 4; ++i) {
    int goff = i * 8192 + tid * 16;
    *(uint4v*)(lds_att + (goff >> 11) * APITCH + (goff & 2047)) = mk[i];
  }
  if (tid < 256) *(float4*)(lds_pos + tid * 4) = pv4;

  uint4v qh[2], ql[2];
#pragma unroll
  for (int cc = 0; cc < 2; ++cc) {
    const float* qp = q + (((size_t)b * LN + l) * HN + h) * EN + cc * 32 + cg * 8;
    cvt8(qp, qh[cc], ql[cc]);
  }

  // K batch-0 prefetch (consumed immediately after bar1)
  uint4v kf0[4][2];
#pragma unroll
  for (int t2 = 0; t2 < 4; ++t2)
#pragma unroll
    for (int cc = 0; cc < 2; ++cc)
      kf0[t2][cc] = *(const uint4v*)(kbb + (size_t)(w * 128 + t2 * 16 + cl) * 64 +
                                     cc * 32 + cg * 8);

  __syncthreads();  // bar1: staging visible

  f32x4 accs[8];

  // ---- QK^T batch 0 (prefetched) ----
#pragma unroll
  for (int t2 = 0; t2 < 4; ++t2) {
    f32x4 acc = f32x4{0.f, 0.f, 0.f, 0.f};
#pragma unroll
    for (int cc = 0; cc < 2; ++cc) {
      bf16x8 kv = __builtin_bit_cast(bf16x8, kf0[t2][cc]);
      acc = __builtin_amdgcn_mfma_f32_16x16x32_bf16(
          kv, __builtin_bit_cast(bf16x8, qh[cc]), acc, 0, 0, 0);
      acc = __builtin_amdgcn_mfma_f32_16x16x32_bf16(
          kv, __builtin_bit_cast(bf16x8, ql[cc]), acc, 0, 0, 0);
    }
    accs[t2] = acc;
  }
  // ---- QK^T batch 1 ----
  {
    uint4v kf[4][2];
#pragma unroll
    for (int t2 = 0; t2 < 4; ++t2)
#pragma unroll
      for (int cc = 0; cc < 2; ++cc)
        kf[t2][cc] = *(const uint4v*)(kbb +
                                      (size_t)(w * 128 + (4 + t2) * 16 + cl) * 64 +
                                      cc * 32 + cg * 8);
#pragma unroll
    for (int t2 = 0; t2 < 4; ++t2) {
      f32x4 acc = f32x4{0.f, 0.f, 0.f, 0.f};
#pragma unroll
      for (int cc = 0; cc < 2; ++cc) {
        bf16x8 kv = __builtin_bit_cast(bf16x8, kf[t2][cc]);
        acc = __builtin_amdgcn_mfma_f32_16x16x32_bf16(
            kv, __builtin_bit_cast(bf16x8, qh[cc]), acc, 0, 0, 0);
        acc = __builtin_amdgcn_mfma_f32_16x16x32_bf16(
            kv, __builtin_bit_cast(bf16x8, ql[cc]), acc, 0, 0, 0);
      }
      accs[4 + t2] = acc;
    }
  }

  // ---- mask (LDS f16) + causal (LDS pos) + max
  const float plr = lds_pos[l];
  const unsigned char* mbase = lds_att + cl * APITCH;

  float mx = -3.0e38f;
#pragma unroll
  for (int tg = 0; tg < 8; ++tg) {
    const int s0 = w * 128 + tg * 16 + cg * 4;
    f16x4 m4 = *(const f16x4*)(mbase + s0 * 2);
    float4 po4 = *(const float4*)(lds_pos + s0);
    float pov[4] = {po4.x, po4.y, po4.z, po4.w};
#pragma unroll
    for (int r = 0; r < 4; ++r) {
      float v = fmaf(accs[tg][r], 0.125f, (float)m4[r]);
      bool maskd = (causal != 0) && (pov[r] > plr);
      v = maskd ? -1.0e30f : v;
      accs[tg][r] = v;
      mx = fmaxf(mx, v);
    }
  }
  mx = fmaxf(mx, __shfl_xor(mx, 16, 64));
  mx = fmaxf(mx, __shfl_xor(mx, 32, 64));
  if (cg == 0) red0[w][cl] = mx;
  __syncthreads();  // bar2
  float bmx = red0[0][cl];
#pragma unroll
  for (int i = 1; i < 8; ++i) bmx = fmaxf(bmx, red0[i][cl]);

  float zz = 0.f, ee = 0.f;
#pragma unroll
  for (int tg = 0; tg < 8; ++tg) {
#pragma unroll
    for (int r = 0; r < 4; ++r) {
      float tt = accs[tg][r] - bmx;
      float ex = __expf(tt);
      zz += ex;
      ee = fmaf(ex, fmaxf(tt, -88.0f), ee);  // guard 0 * -1e30
      accs[tg][r] = ex;
    }
  }
  zz += __shfl_xor(zz, 16, 64);
  zz += __shfl_xor(zz, 32, 64);
  ee += __shfl_xor(ee, 16, 64);
  ee += __shfl_xor(ee, 32, 64);
  if (cg == 0) { redZ[w][cl] = zz; redE[w][cl] = ee; }

  // ---- vT batch-0 prefetch (independent of LDS; hides under bar3/bar4)
  const int et = w & 3, sh = w >> 2;
  const unsigned short* vbb =
      vT + ((size_t)(b * 8 + h) * 64 + et * 16 + cl) * 1024 + sh * 512;
  uint4v vf0[8];
#pragma unroll
  for (int j = 0; j < 8; ++j)
    vf0[j] = *(const uint4v*)(vbb + j * 32 + cg * 8);

  __syncthreads();  // bar3
  float Z = redZ[0][cl], E = redE[0][cl];
#pragma unroll
  for (int i = 1; i < 8; ++i) { Z += redZ[i][cl]; E += redE[i][cl]; }
  const float rz = __fdividef(1.0f, Z);
  const float entv = __logf(Z) - E * rz;

  // ---- normalized bf16 att into LDS (overwrites mask region)
  unsigned char* arow = lds_att + cl * APITCH;
#pragma unroll
  for (int tg = 0; tg < 8; ++tg) {
    const int s0 = w * 128 + tg * 16 + cg * 4;
    float ax = accs[tg][0] * rz, ay = accs[tg][1] * rz;
    float az = accs[tg][2] * rz, aw = accs[tg][3] * rz;
    uint2v pk = uint2v{
        (__float_as_uint(ax) >> 16) | (__float_as_uint(ay) & 0xffff0000u),
        (__float_as_uint(az) >> 16) | (__float_as_uint(aw) & 0xffff0000u)};
    *(uint2v*)(arow + s0 * 2) = pk;
  }

  __syncthreads();  // bar4: full att tile visible

  // ---- PV: wave w -> e-tile et, s-half sh. Batch 0 uses prefetched vf0.
  f32x4 acc0 = f32x4{0.f, 0.f, 0.f, 0.f};
  f32x4 acc1 = f32x4{0.f, 0.f, 0.f, 0.f};
  {
    uint4v af[8];
#pragma unroll
    for (int j = 0; j < 8; ++j)
      af[j] = *(const uint4v*)(lds_att + cl * APITCH +
                               (sh * 512 + j * 32 + cg * 8) * 2);
#pragma unroll
    for (int j = 0; j < 8; ++j) {
      bf16x8 a8 = __builtin_bit_cast(bf16x8, vf0[j]);
      bf16x8 b8 = __builtin_bit_cast(bf16x8, af[j]);
      if (j & 1)
        acc1 = __builtin_amdgcn_mfma_f32_16x16x32_bf16(a8, b8, acc1, 0, 0, 0);
      else
        acc0 = __builtin_amdgcn_mfma_f32_16x16x32_bf16(a8, b8, acc0, 0, 0, 0);
    }
  }
  {
    uint4v vf[8], af[8];
#pragma unroll
    for (int j = 0; j < 8; ++j) {
      const int sc = 8 + j;
      vf[j] = *(const uint4v*)(vbb + sc * 32 + cg * 8);
      af[j] = *(const uint4v*)(lds_att + cl * APITCH +
                               (sh * 512 + sc * 32 + cg * 8) * 2);
    }
#pragma unroll
    for (int j = 0; j < 8; ++j) {
      bf16x8 a8 = __builtin_bit_cast(bf16x8, vf[j]);
      bf16x8 b8 = __builtin_bit_cast(bf16x8, af[j]);
      if (j & 1)
        acc1 = __builtin_amdgcn_mfma_f32_16x16x32_bf16(a8, b8, acc1, 0, 0, 0);
      else
        acc0 = __builtin_amdgcn_mfma_f32_16x16x32_bf16(a8, b8, acc0, 0, 0, 0);
    }
  }
  f32x4 sum = acc0 + acc1;

  // partials to dedicated LDS (att tile stays intact for the final write)
  *(f32x4*)(lds_part + w * 1024 + cl * 64 + cg * 16) = sum;

  __syncthreads();  // bar5: LAST barrier — no output store issued yet

  // ---- all global output stores issued after the last barrier ----
  // V: cross s-half reduce + coalesced NT store
  if (tid < 256) {
    const int l_ = tid >> 4, e4 = tid & 15, et_ = e4 >> 2;
    f32x4 p0 = *(const f32x4*)(lds_part + et_ * 1024 + l_ * 64 + (e4 & 3) * 16);
    f32x4 p1 = *(const f32x4*)(lds_part + (et_ + 4) * 1024 + l_ * 64 + (e4 & 3) * 16);
    f32x4 s = p0 + p1;
    float* dst = out + (((size_t)b * LN + lb * 16 + l_) * HN + h) * EN + e4 * 4;
    __builtin_nontemporal_store(s, (f32x4*)dst);
  }
  // entropy
  if (w == 0 && cg == 0)
    out[OFF_ENT + ((size_t)b * HN + h) * LN + l] = entv;
  // att fp32: wave w -> rows w*2, w*2+1 (LDS tile intact)
  {
    float* abase = out + OFF_ATT + (((size_t)b * HN + h) * LN + lb * 16) * SN;
#pragma unroll
    for (int rr = 0; rr < 2; ++rr) {
      const int row = w * 2 + rr;
      const unsigned char* src = lds_att + row * APITCH;
      float* dst = abase + (size_t)row * SN;
#pragma unroll
      for (int it = 0; it < 4; ++it) {
        uint2v pk = *(const uint2v*)(src + it * 512 + c * 8);
        f32x4 o = f32x4{__uint_as_float(pk.x << 16),
                        __uint_as_float(pk.x & 0xffff0000u),
                        __uint_as_float(pk.y << 16),
                        __uint_as_float(pk.y & 0xffff0000u)};
        __builtin_nontemporal_store(o, (f32x4*)(dst + it * 256 + c * 4));
      }
    }
  }
}

extern "C" void kernel_launch(void* const* d_in, const int* in_sizes, int n_in,
                              void* d_out, int out_size, void* d_ws, size_t ws_size,
                              hipStream_t stream) {
  (void)in_sizes; (void)n_in; (void)out_size; (void)ws_size;
  const float* q   = (const float*)d_in[0];
  const float* k   = (const float*)d_in[1];
  const float* v   = (const float*)d_in[2];
  const float* pos = (const float*)d_in[3];
  const float* phi = (const float*)d_in[4];
  const float* u   = (const float*)d_in[5];
  const float* lt  = (const float*)d_in[6];
  const float* th  = (const float*)d_in[7];
  const int*   cm  = (const int*)d_in[8];
  float* out = (float*)d_out;

  _Float16* mw = (_Float16*)((char*)d_ws + WS_MW);
  unsigned short* kb = (unsigned short*)((char*)d_ws + WS_KB);
  unsigned short* vT = (unsigned short*)((char*)d_ws + WS_VT);

  k_prep<<<dim3(10240), dim3(256), 0, stream>>>(k, v, phi, u, lt, th, mw, kb, vT);
  k_fused<<<dim3(256, 8, 1), dim3(512), 0, stream>>>(q, kb, vT, mw, pos, cm, out);
}